// Round 7
// baseline (246.866 us; speedup 1.0000x reference)
//
#include <hip/hip_runtime.h>
#include <stdint.h>

// irreps linear: 128x0e+128x1o+128x2e, per-block y[z,w,i] = a * sum_u W[u,w] x[z,u,i]
// GEMMs with M=(i,z), N=w(128), K=u(128). bf16 MFMA, f32 accum.
// Persistent WGs (1024 = 4/CU), W in registers, double-buffered LDS x,
// register prefetch, dense per-lane stores.
// r7: (a) raw lgkmcnt-only barrier (no vmcnt drain -> stores fire-and-forget,
//     prefetch loads survive the barrier); (b) load-issue moved to after
//     write_tile (same vf regs, WAR) so loads are in flight across
//     store+barrier+MFMA instead of MFMA only.

#define NROWS 100000
#define ROWLEN 1152

typedef __attribute__((ext_vector_type(8))) short bf16x8;
typedef __attribute__((ext_vector_type(4))) float f32x4;
typedef __attribute__((ext_vector_type(4))) ushort u16x4;
typedef float f32x4u __attribute__((ext_vector_type(4), aligned(4)));
typedef float f32x2u __attribute__((ext_vector_type(2), aligned(4)));

__device__ __forceinline__ ushort f2b(float f) {
  union { float f; uint32_t u; } v; v.f = f;
  uint32_t r = v.u + 0x7FFFu + ((v.u >> 16) & 1u);  // RNE; inputs finite
  return (ushort)(r >> 16);
}

// Wave-LDS-visibility barrier WITHOUT vmcnt drain. Global loads are
// consumed wave-privately (VGPRs) and stores need no cross-wave visibility,
// so only lgkmcnt must reach 0 before the barrier.
__device__ __forceinline__ void wg_barrier() {
  asm volatile("s_waitcnt lgkmcnt(0)\n\ts_barrier" ::: "memory");
}

// ---- staging helpers ----------------------------------------------------
template<int D, int TM, bool G>
__device__ __forceinline__ void load_tile(const float* __restrict__ xb, int t,
                                          int tid, f32x4 (&vf)[TM / 8][D])
{
  #pragma unroll
  for (int p = 0; p < TM / 8; ++p) {
    int ch = p * 256 + tid;
    int zl = ch >> 5, cc = ch & 31;
    int z  = t * TM + zl;
    const float* src = xb + (size_t)z * ROWLEN + cc * 4 * D;
    #pragma unroll
    for (int j = 0; j < D; ++j) {
      f32x4 v = {0.f, 0.f, 0.f, 0.f};
      if (!G || z < NROWS) v = *(const f32x4*)(src + 4 * j);
      vf[p][j] = v;
    }
  }
}

// LDS A layout: [m][u] bf16, row = 256 B, 16B-chunk XOR swizzle chunk^=(m&7).
template<int D, int TM>
__device__ __forceinline__ void write_tile(char* __restrict__ buf, int tid,
                                           f32x4 (&vf)[TM / 8][D])
{
  #pragma unroll
  for (int p = 0; p < TM / 8; ++p) {
    int ch = p * 256 + tid;
    int zl = ch >> 5, cc = ch & 31;
    #pragma unroll
    for (int i = 0; i < D; ++i) {
      int m = i * TM + zl;
      u16x4 pk;
      #pragma unroll
      for (int u = 0; u < 4; ++u) {
        int e = i + D * u;            // compile-time after unroll
        pk[u] = f2b(vf[p][e >> 2][e & 3]);
      }
      int byte = m * 256 + ((((cc >> 1) ^ (m & 7)) << 4) | ((cc & 1) << 3));
      *(u16x4*)(buf + byte) = pk;
    }
  }
}

// ---- stores --------------------------------------------------------------
template<bool G, int TM, int MTILES>
__device__ __forceinline__ void store_d1(float* __restrict__ ob, int z0,
                                         int lane, int nbase,
                                         f32x4 (&acc)[MTILES][2])
{
  const int rbase = ((lane >> 4) & 3) << 2;
  #pragma unroll
  for (int mt = 0; mt < MTILES; ++mt) {
    #pragma unroll
    for (int r = 0; r < 4; ++r) {
      int zl = mt * 16 + rbase + r;
      int z  = z0 + zl;
      if (G && z >= NROWS) continue;
      float* orow = ob + (size_t)z * ROWLEN;
      orow[nbase]      = acc[mt][0][r];
      orow[nbase + 16] = acc[mt][1][r];
    }
  }
}

// TM=16 paths: lane holds all D consecutive cols (i == mt) for its (n, z).
template<int D, int MTILES>
__device__ __forceinline__ void store_dense(float* __restrict__ ob, int z0,
                                            int lane, int nbase,
                                            f32x4 (&acc)[MTILES][2])
{
  const int rbase = ((lane >> 4) & 3) << 2;
  #pragma unroll
  for (int nt = 0; nt < 2; ++nt) {
    const int colb = (nbase + nt * 16) * D;
    #pragma unroll
    for (int r = 0; r < 4; ++r) {
      int z = z0 + rbase + r;
      float* p = ob + (size_t)z * ROWLEN + colb;
      if (D == 5) {
        f32x4u v4 = { acc[0][nt][r], acc[1][nt][r], acc[2][nt][r], acc[3][nt][r] };
        *(f32x4u*)p = v4;
        p[4] = acc[4][nt][r];
      } else {  // D == 3
        f32x2u v2 = { acc[0][nt][r], acc[1][nt][r] };
        *(f32x2u*)p = v2;
        p[2] = acc[2][nt][r];
      }
    }
  }
}

// ---- persistent per-irrep path ------------------------------------------
template<int D, int TM, bool GUARD, int NWGS>
__device__ __forceinline__ void linpath(const float* __restrict__ xb,
                                        const float* __restrict__ wb,
                                        float* __restrict__ ob,
                                        int wgid, char* lds)
{
  constexpr int MT     = TM * D;
  constexpr int MTILES = MT / 16;
  constexpr int PT     = TM / 8;
  constexpr int NTILES = (NROWS + TM - 1) / TM;
  constexpr int BUFB   = MT * 256;
  constexpr float ALPHA = 0.088388347648318447f;  // 128^-0.5

  const int tid   = threadIdx.x;
  const int lane  = tid & 63;
  const int wv    = tid >> 6;
  const int l15   = lane & 15;
  const int kr    = ((lane >> 4) & 3) << 3;
  const int nbase = (wv << 5) + l15;

  // weights -> registers once per WG (K=128 x N=32 per wave), ALPHA folded
  bf16x8 bfr[2][4];
  #pragma unroll
  for (int nt = 0; nt < 2; ++nt)
    #pragma unroll
    for (int ks = 0; ks < 4; ++ks)
      #pragma unroll
      for (int j = 0; j < 8; ++j)
        bfr[nt][ks][j] =
            (short)f2b(wb[(ks * 32 + kr + j) * 128 + nbase + nt * 16] * ALPHA);

  char* buf0 = lds;
  char* buf1 = lds + BUFB;

  // prologue: stage tile t0, then issue prefetch of t0+NWGS (survives barrier)
  const int t0 = wgid;
  f32x4 vf[PT][D];
  if (GUARD && t0 == NTILES - 1) load_tile<D, TM, true>(xb, t0, tid, vf);
  else                           load_tile<D, TM, false>(xb, t0, tid, vf);
  write_tile<D, TM>(buf0, tid, vf);
  if (t0 + NWGS < NTILES) {
    if (GUARD && t0 + NWGS == NTILES - 1) load_tile<D, TM, true>(xb, t0 + NWGS, tid, vf);
    else                                  load_tile<D, TM, false>(xb, t0 + NWGS, tid, vf);
  }
  wg_barrier();

  int cur = 0;
  for (int t = t0; t < NTILES; t += NWGS) {
    char* bc = cur ? buf1 : buf0;
    char* bn = cur ? buf0 : buf1;
    const int tn  = t + NWGS;
    const int tnn = t + 2 * NWGS;

    // 1. MFMA on current buffer
    f32x4 acc[MTILES][2];
    #pragma unroll
    for (int mt = 0; mt < MTILES; ++mt) {
      acc[mt][0] = f32x4{0.f, 0.f, 0.f, 0.f};
      acc[mt][1] = f32x4{0.f, 0.f, 0.f, 0.f};
    }
    #pragma unroll
    for (int ks = 0; ks < 4; ++ks) {
      const int chunkbase = ks * 4 + ((lane >> 4) & 3);  // (ks*32+kr)>>3
      #pragma unroll
      for (int mt = 0; mt < MTILES; ++mt) {
        int m = (mt << 4) + l15;
        int byte = m * 256 + ((chunkbase ^ (m & 7)) << 4);
        bf16x8 a = *(const bf16x8*)(bc + byte);
        acc[mt][0] = __builtin_amdgcn_mfma_f32_16x16x32_bf16(a, bfr[0][ks], acc[mt][0], 0, 0, 0);
        acc[mt][1] = __builtin_amdgcn_mfma_f32_16x16x32_bf16(a, bfr[1][ks], acc[mt][1], 0, 0, 0);
      }
    }

    // 2. convert + LDS-write next tile (consumes vf)
    if (tn < NTILES) write_tile<D, TM>(bn, tid, vf);

    // 3. re-issue vf with tile t+2 (WAR on vf regs; in flight across
    //    store + barrier + next MFMA)
    if (tnn < NTILES) {
      if (GUARD && tnn == NTILES - 1) load_tile<D, TM, true>(xb, tnn, tid, vf);
      else                            load_tile<D, TM, false>(xb, tnn, tid, vf);
    }

    // 4. store current tile's output (fire-and-forget; no drain at barrier)
    if (D == 1) {
      if (GUARD && t == NTILES - 1)
        store_d1<true, TM, MTILES>(ob, t * TM, lane, nbase, acc);
      else
        store_d1<false, TM, MTILES>(ob, t * TM, lane, nbase, acc);
    } else {
      store_dense<D, MTILES>(ob, t * TM, lane, nbase, acc);
    }

    wg_barrier();
    cur ^= 1;
  }
}

// WG split proportional to bytes (1:3:5), grid = 1024 = 4 WGs/CU.
constexpr int NW1 = 114;   // D=1, TM=64, 1563 tiles
constexpr int NW3 = 341;   // D=3, TM=16, 6250 tiles
constexpr int NW5 = 569;   // D=5, TM=16, 6250 tiles

__global__ __launch_bounds__(256, 4)
void linear_irreps_kernel(const float* __restrict__ x, const float* __restrict__ w,
                          float* __restrict__ out)
{
  extern __shared__ __align__(16) char lds[];
  int wg = blockIdx.x;
  if (wg < NW1) {
    linpath<1, 64, true,  NW1>(x,       w,         out,       wg,             lds);
  } else if (wg < NW1 + NW3) {
    linpath<3, 16, false, NW3>(x + 128, w + 16384, out + 128, wg - NW1,       lds);
  } else {
    linpath<5, 16, false, NW5>(x + 512, w + 32768, out + 512, wg - NW1 - NW3, lds);
  }
}

extern "C" void kernel_launch(void* const* d_in, const int* in_sizes, int n_in,
                              void* d_out, int out_size, void* d_ws, size_t ws_size,
                              hipStream_t stream) {
  const float* x = (const float*)d_in[0];
  const float* w = (const float*)d_in[1];
  float* out = (float*)d_out;
  (void)in_sizes; (void)n_in; (void)out_size; (void)d_ws; (void)ws_size;
  dim3 grid(NW1 + NW3 + NW5);
  dim3 block(256);
  hipLaunchKernelGGL(linear_irreps_kernel, grid, block, 40960, stream, x, w, out);
}

// Round 8
// 202.558 us; speedup vs baseline: 1.2187x; 1.2187x over previous
//
#include <hip/hip_runtime.h>
#include <stdint.h>

// irreps linear: 128x0e+128x1o+128x2e, per-block y[z,w,i] = a * sum_u W[u,w] x[z,u,i]
// GEMMs with M=(i,z), N=w(128), K=u(128). bf16 MFMA, f32 accum.
// Structure = round-6 (best known, 201 us): persistent WGs (1024 = 4/CU),
// W in registers, double-buffered LDS x, register prefetch issued BEFORE the
// MFMA and consumed right after (compiler-friendly liveness; r7 taught us
// moving it breaks regalloc), dense per-lane stores, ONE __syncthreads/tile.
// r8: output stores are NON-TEMPORAL (evict-first) so the 461 MB write stream
// stops evicting x from Infinity Cache between graph replays (FETCH_SIZE
// swung 227-418 MB across rounds = L3 retention of x is real and contested).

#define NROWS 100000
#define ROWLEN 1152

typedef __attribute__((ext_vector_type(8))) short bf16x8;
typedef __attribute__((ext_vector_type(4))) float f32x4;
typedef __attribute__((ext_vector_type(4))) ushort u16x4;
typedef float f32x4u __attribute__((ext_vector_type(4), aligned(4)));
typedef float f32x2u __attribute__((ext_vector_type(2), aligned(4)));

__device__ __forceinline__ ushort f2b(float f) {
  union { float f; uint32_t u; } v; v.f = f;
  uint32_t r = v.u + 0x7FFFu + ((v.u >> 16) & 1u);  // RNE; inputs finite
  return (ushort)(r >> 16);
}

// ---- staging helpers ----------------------------------------------------
template<int D, int TM, bool G>
__device__ __forceinline__ void load_tile(const float* __restrict__ xb, int t,
                                          int tid, f32x4 (&vf)[TM / 8][D])
{
  #pragma unroll
  for (int p = 0; p < TM / 8; ++p) {
    int ch = p * 256 + tid;
    int zl = ch >> 5, cc = ch & 31;
    int z  = t * TM + zl;
    const float* src = xb + (size_t)z * ROWLEN + cc * 4 * D;
    #pragma unroll
    for (int j = 0; j < D; ++j) {
      f32x4 v = {0.f, 0.f, 0.f, 0.f};
      if (!G || z < NROWS) v = *(const f32x4*)(src + 4 * j);
      vf[p][j] = v;
    }
  }
}

// LDS A layout: [m][u] bf16, row = 256 B, 16B-chunk XOR swizzle chunk^=(m&7).
template<int D, int TM>
__device__ __forceinline__ void write_tile(char* __restrict__ buf, int tid,
                                           f32x4 (&vf)[TM / 8][D])
{
  #pragma unroll
  for (int p = 0; p < TM / 8; ++p) {
    int ch = p * 256 + tid;
    int zl = ch >> 5, cc = ch & 31;
    #pragma unroll
    for (int i = 0; i < D; ++i) {
      int m = i * TM + zl;
      u16x4 pk;
      #pragma unroll
      for (int u = 0; u < 4; ++u) {
        int e = i + D * u;            // compile-time after unroll
        pk[u] = f2b(vf[p][e >> 2][e & 3]);
      }
      int byte = m * 256 + ((((cc >> 1) ^ (m & 7)) << 4) | ((cc & 1) << 3));
      *(u16x4*)(buf + byte) = pk;
    }
  }
}

// ---- stores (all non-temporal: out is write-once, never re-read) ---------
template<bool G, int TM, int MTILES>
__device__ __forceinline__ void store_d1(float* __restrict__ ob, int z0,
                                         int lane, int nbase,
                                         f32x4 (&acc)[MTILES][2])
{
  const int rbase = ((lane >> 4) & 3) << 2;
  #pragma unroll
  for (int mt = 0; mt < MTILES; ++mt) {
    #pragma unroll
    for (int r = 0; r < 4; ++r) {
      int zl = mt * 16 + rbase + r;
      int z  = z0 + zl;
      if (G && z >= NROWS) continue;
      float* orow = ob + (size_t)z * ROWLEN;
      __builtin_nontemporal_store(acc[mt][0][r], orow + nbase);
      __builtin_nontemporal_store(acc[mt][1][r], orow + nbase + 16);
    }
  }
}

// TM=16 paths: lane holds all D consecutive cols (i == mt) for its (n, z).
template<int D, int MTILES>
__device__ __forceinline__ void store_dense(float* __restrict__ ob, int z0,
                                            int lane, int nbase,
                                            f32x4 (&acc)[MTILES][2])
{
  const int rbase = ((lane >> 4) & 3) << 2;
  #pragma unroll
  for (int nt = 0; nt < 2; ++nt) {
    const int colb = (nbase + nt * 16) * D;
    #pragma unroll
    for (int r = 0; r < 4; ++r) {
      int z = z0 + rbase + r;
      float* p = ob + (size_t)z * ROWLEN + colb;
      if (D == 5) {
        f32x4u v4 = { acc[0][nt][r], acc[1][nt][r], acc[2][nt][r], acc[3][nt][r] };
        __builtin_nontemporal_store(v4, (f32x4u*)p);
        __builtin_nontemporal_store(acc[4][nt][r], p + 4);
      } else {  // D == 3
        f32x2u v2 = { acc[0][nt][r], acc[1][nt][r] };
        __builtin_nontemporal_store(v2, (f32x2u*)p);
        __builtin_nontemporal_store(acc[2][nt][r], p + 2);
      }
    }
  }
}

// ---- persistent per-irrep path ------------------------------------------
template<int D, int TM, bool GUARD, int NWGS>
__device__ __forceinline__ void linpath(const float* __restrict__ xb,
                                        const float* __restrict__ wb,
                                        float* __restrict__ ob,
                                        int wgid, char* lds)
{
  constexpr int MT     = TM * D;
  constexpr int MTILES = MT / 16;
  constexpr int PT     = TM / 8;
  constexpr int NTILES = (NROWS + TM - 1) / TM;
  constexpr int BUFB   = MT * 256;
  constexpr float ALPHA = 0.088388347648318447f;  // 128^-0.5

  const int tid   = threadIdx.x;
  const int lane  = tid & 63;
  const int wv    = tid >> 6;
  const int l15   = lane & 15;
  const int kr    = ((lane >> 4) & 3) << 3;
  const int nbase = (wv << 5) + l15;

  // weights -> registers once per WG (K=128 x N=32 per wave), ALPHA folded
  bf16x8 bfr[2][4];
  #pragma unroll
  for (int nt = 0; nt < 2; ++nt)
    #pragma unroll
    for (int ks = 0; ks < 4; ++ks)
      #pragma unroll
      for (int j = 0; j < 8; ++j)
        bfr[nt][ks][j] =
            (short)f2b(wb[(ks * 32 + kr + j) * 128 + nbase + nt * 16] * ALPHA);

  char* buf0 = lds;
  char* buf1 = lds + BUFB;

  // prologue: stage first tile
  int t0 = wgid;
  {
    f32x4 vf[PT][D];
    if (GUARD && t0 == NTILES - 1) load_tile<D, TM, true>(xb, t0, tid, vf);
    else                           load_tile<D, TM, false>(xb, t0, tid, vf);
    write_tile<D, TM>(buf0, tid, vf);
  }
  __syncthreads();

  int cur = 0;
  for (int t = t0; t < NTILES; t += NWGS) {
    char* bc = cur ? buf1 : buf0;
    char* bn = cur ? buf0 : buf1;
    const int tn = t + NWGS;
    const bool have = tn < NTILES;

    // 1. issue next tile's global loads into regs (latency hides under MFMA)
    f32x4 vf[PT][D];
    if (have) {
      if (GUARD && tn == NTILES - 1) load_tile<D, TM, true>(xb, tn, tid, vf);
      else                           load_tile<D, TM, false>(xb, tn, tid, vf);
    }

    // 2. MFMA on current buffer
    f32x4 acc[MTILES][2];
    #pragma unroll
    for (int mt = 0; mt < MTILES; ++mt) {
      acc[mt][0] = f32x4{0.f, 0.f, 0.f, 0.f};
      acc[mt][1] = f32x4{0.f, 0.f, 0.f, 0.f};
    }
    #pragma unroll
    for (int ks = 0; ks < 4; ++ks) {
      const int chunkbase = ks * 4 + ((lane >> 4) & 3);  // (ks*32+kr)>>3
      #pragma unroll
      for (int mt = 0; mt < MTILES; ++mt) {
        int m = (mt << 4) + l15;
        int byte = m * 256 + ((chunkbase ^ (m & 7)) << 4);
        bf16x8 a = *(const bf16x8*)(bc + byte);
        acc[mt][0] = __builtin_amdgcn_mfma_f32_16x16x32_bf16(a, bfr[0][ks], acc[mt][0], 0, 0, 0);
        acc[mt][1] = __builtin_amdgcn_mfma_f32_16x16x32_bf16(a, bfr[1][ks], acc[mt][1], 0, 0, 0);
      }
    }

    // 3. convert + LDS-write next tile (global loads have landed by now)
    if (have) write_tile<D, TM>(bn, tid, vf);

    // 4. store current tile's output (dense per-lane spans, non-temporal)
    if (D == 1) {
      if (GUARD && t == NTILES - 1)
        store_d1<true, TM, MTILES>(ob, t * TM, lane, nbase, acc);
      else
        store_d1<false, TM, MTILES>(ob, t * TM, lane, nbase, acc);
    } else {
      store_dense<D, MTILES>(ob, t * TM, lane, nbase, acc);
    }

    __syncthreads();
    cur ^= 1;
  }
}

// WG split proportional to bytes (1:3:5), grid = 1024 = 4 WGs/CU.
constexpr int NW1 = 114;   // D=1, TM=64, 1563 tiles
constexpr int NW3 = 341;   // D=3, TM=16, 6250 tiles
constexpr int NW5 = 569;   // D=5, TM=16, 6250 tiles

__global__ __launch_bounds__(256, 4)
void linear_irreps_kernel(const float* __restrict__ x, const float* __restrict__ w,
                          float* __restrict__ out)
{
  extern __shared__ __align__(16) char lds[];
  int wg = blockIdx.x;
  if (wg < NW1) {
    linpath<1, 64, true,  NW1>(x,       w,         out,       wg,             lds);
  } else if (wg < NW1 + NW3) {
    linpath<3, 16, false, NW3>(x + 128, w + 16384, out + 128, wg - NW1,       lds);
  } else {
    linpath<5, 16, false, NW5>(x + 512, w + 32768, out + 512, wg - NW1 - NW3, lds);
  }
}

extern "C" void kernel_launch(void* const* d_in, const int* in_sizes, int n_in,
                              void* d_out, int out_size, void* d_ws, size_t ws_size,
                              hipStream_t stream) {
  const float* x = (const float*)d_in[0];
  const float* w = (const float*)d_in[1];
  float* out = (float*)d_out;
  (void)in_sizes; (void)n_in; (void)out_size; (void)d_ws; (void)ws_size;
  dim3 grid(NW1 + NW3 + NW5);
  dim3 block(256);
  hipLaunchKernelGGL(linear_irreps_kernel, grid, block, 40960, stream, x, w, out);
}